// Round 4
// baseline (344.302 us; speedup 1.0000x reference)
//
#include <hip/hip_runtime.h>
#include <cmath>

// Problem constants
#define B_TOTAL 262144
#define D 16
#define TE 3
#define H 64

#define TPB 16                       // b-tiles (of 16 rows) per wave
#define NBX (B_TOTAL / 16 / TPB)     // 1024 blocks in x
#define NBY 4                        // d-groups of 4 (4 waves/block, one d each)

#define LOG2E 1.44269504088896340736f
#define LN2   0.693147180559945309417f

// A-frag staging stride in dwords. 10 (40B): banks 10*lm mod 32 all distinct
// for lm=0..15 -> conflict-free ds_read_b64; 8B alignment holds.
#define ARS 10

#define OSTRIDE (TPB * 16 * 4)       // one obuf half (floats)

typedef _Float16 half8  __attribute__((ext_vector_type(8)));
typedef _Float16 half4  __attribute__((ext_vector_type(4)));
typedef __fp16   fp16x2 __attribute__((ext_vector_type(2)));   // cvt_pkrtz return type
typedef float    f32x4  __attribute__((ext_vector_type(4)));
typedef unsigned int uint32;

// log2-domain softplus: log2(1 + 2^xs). Scale factors pre-folded into weights:
// W1,b1,b2 carry log2e; W3 carries ln2; ln2*log2e==1 so W2 is raw.
__device__ __forceinline__ float sp_log2(float xs) {
    return __builtin_amdgcn_logf(1.0f + __builtin_amdgcn_exp2f(xs));
}
// exact softplus for the final (unscaled) output
__device__ __forceinline__ float softplus_full(float x) {
    float e = __builtin_amdgcn_exp2f(-fabsf(x) * LOG2E);
    return fmaxf(x, 0.0f) + LN2 * __builtin_amdgcn_logf(1.0f + e);
}

// R13 = R12 (fully register-resident, both layers swapped) + two issue-cycle
// levers found in the R12 counter audit (VALUBusy includes MFMA issue; K=16
// MFMA costs the same issue slots as K=32):
//  1. Layer 2 as 8x mfma_16x16x32_f16 instead of 16x K=16, via a PERMUTED
//     hid->k mapping chosen so each lane's in-register h1 values already sit
//     in the K=32 B-frag slots:  hid_in(ks,q,j) = 32ks + 16(j>>2) + 4q + (j&3).
//     B operand = {hb[c=2ks], hb[c=2ks+1]} aliased as half8 — zero data
//     movement; only the W2 setup gather changes to match. -8 MFMA/tile.
//  2. __launch_bounds__(256,6): R10-R12 show occupancy tracks the bound
//     (5->49%, 4->40%); lift residency to cover the L1->sp->L2 dependency
//     chain (18% issue-idle at 3.2 waves/SIMD). VGPR cap ~84 vs 60 used.
__global__ __launch_bounds__(256, 6) void DiagonalVariance_kernel(
    const float* __restrict__ t,   // [B, TE]
    const float* __restrict__ y,   // [B, D]
    const float* __restrict__ W1,  // [D, 4, 64]
    const float* __restrict__ b1,  // [D, 64]
    const float* __restrict__ W2,  // [D, 64, 64]
    const float* __restrict__ b2,  // [D, 64]
    const float* __restrict__ W3,  // [D, 64, 1]
    const float* __restrict__ b3,  // [D, 1]
    float* __restrict__ out)       // [B, D]
{
    __shared__ __align__(16) float obuf[2 * OSTRIDE];       // 8 KB: [half][row_local][dd]
    __shared__ __align__(16) uint32 abuf[256 * ARS];        // 10 KB: [row][{u0_d,u1}x4]

    const int wave = threadIdx.x >> 6;
    const int lane = threadIdx.x & 63;
    const int q    = lane >> 4;
    const int lm   = lane & 15;
    const int d    = blockIdx.y * 4 + wave;
    const bool q0  = (q == 0);

    // ---- cooperative input staging: thread i pre-packs row i's x-frag ----
    {
        const int i    = threadIdx.x;
        const int grow = blockIdx.x * 256 + i;
        const f32x4 yv = *(const f32x4*)(y + grow * D + blockIdx.y * 4);
        const float* tpp = t + grow * TE;
        const float tt0 = tpp[0], tt1 = tpp[1], tt2 = tpp[2];
        const uint32 u1 = __builtin_bit_cast(uint32, __builtin_amdgcn_cvt_pkrtz(tt1, tt2));
        uint32* ab = abuf + i * ARS;
        ab[0] = __builtin_bit_cast(uint32, __builtin_amdgcn_cvt_pkrtz(yv.x, tt0)); ab[1] = u1;
        ab[2] = __builtin_bit_cast(uint32, __builtin_amdgcn_cvt_pkrtz(yv.y, tt0)); ab[3] = u1;
        ab[4] = __builtin_bit_cast(uint32, __builtin_amdgcn_cvt_pkrtz(yv.z, tt0)); ab[5] = u1;
        ab[6] = __builtin_bit_cast(uint32, __builtin_amdgcn_cvt_pkrtz(yv.w, tt0)); ab[7] = u1;
    }

    const float* __restrict__ W1d = W1 + d * (4 * H);
    const float* __restrict__ b1d = b1 + d * H;
    const float* __restrict__ W2d = W2 + d * (H * H);
    const float* __restrict__ b2d = b2 + d * H;
    const float* __restrict__ W3d = W3 + d * H;

    // ---------------- one-time per-wave fragment setup ----------------
    // W1 as L1 A-operand: A[row=hid(16nt+lm)][k=4q+i] = W1[k][hid]*log2e,
    // bias b1*log2e at k=4 (q1,i=0); k>=5 rows zero (kill x garbage lanes).
    half4 w1f[4];
    #pragma unroll
    for (int nt = 0; nt < 4; ++nt) {
        #pragma unroll
        for (int i = 0; i < 4; ++i) {
            const int h = 16 * nt + lm;
            float v = 0.0f;
            if (q == 0)           v = W1d[i * H + h] * LOG2E;
            if (q == 1 && i == 0) v = b1d[h] * LOG2E;
            w1f[nt][i] = (_Float16)v;
        }
    }

    // W2 as L2 A-operand for the K=32 swapped MFMA with permuted K:
    // lane(q,lm) element j holds A[row=hid_out=16nt+lm][k'=8q+j] where the
    // permuted slot k' carries input hid_in = 32ks + 16(j>>2) + 4q + (j&3).
    half8 w2a[2][4];
    #pragma unroll
    for (int ks = 0; ks < 2; ++ks)
        #pragma unroll
        for (int nt = 0; nt < 4; ++nt)
            #pragma unroll
            for (int j = 0; j < 8; ++j)
                w2a[ks][nt][j] = (_Float16)
                    W2d[(32 * ks + 16 * (j >> 2) + 4 * q + (j & 3)) * H + 16 * nt + lm];

    // L2 C operand: b2*log2e, row-indexed (output row = hid_out = 16nt+4q+r).
    const f32x4 ZC = {0.f, 0.f, 0.f, 0.f};
    f32x4 b2c[4];
    #pragma unroll
    for (int nt = 0; nt < 4; ++nt) {
        f32x4 bv = *(const f32x4*)(b2d + 16 * nt + 4 * q);
        b2c[nt] = (f32x4){bv.x * LOG2E, bv.y * LOG2E, bv.z * LOG2E, bv.w * LOG2E};
    }

    // W3*ln2, row-indexed the same way (hid = 16nt+4q+r), for the VALU L3.
    f32x4 w3l[4];
    #pragma unroll
    for (int nt = 0; nt < 4; ++nt) {
        f32x4 wv = *(const f32x4*)(W3d + 16 * nt + 4 * q);
        w3l[nt] = (f32x4){wv.x * LN2, wv.y * LN2, wv.z * LN2, wv.w * LN2};
    }

    // b3 enters the reduce exactly once: init on q0 lanes only.
    const float sInit = ((lane & 48) == 0) ? b3[d] : 0.0f;

    // staged x-frag base for this wave: + tg*16*ARS per tile (imm offset)
    const uint32* const ard = abuf + lm * ARS + 2 * wave;

    __syncthreads();   // staging visible to all waves

    // ---- cross-tile x-frag prefetch ----
    uint32 a0n = ard[0];
    uint32 a1n = ard[1];

    #pragma unroll 1
    for (int tg = 0; tg < TPB; ++tg) {
        const uint32 a0 = a0n;
        const uint32 a1 = a1n;
        {   // issue next tile's read now; latency hides under this tile
            const int tn = (tg + 1 < TPB) ? (tg + 1) : tg;
            a0n = ard[tn * 16 * ARS + 0];
            a1n = ard[tn * 16 * ARS + 1];
        }
        union { half4 h; uint32 u[2]; } af;
        af.u[0] = q0 ? a0 : 0x00003C00u;   // q1: {1.0h,0} bias row k=4
        af.u[1] = q0 ? a1 : 0u;            // q2/q3 garbage killed by zero A rows

        // ---- layer 1, swapped: acc1[c] = D[hid=16c+4q+r][batch=lm] ----
        f32x4 acc1[4];
        #pragma unroll
        for (int c = 0; c < 4; ++c)
            acc1[c] = __builtin_amdgcn_mfma_f32_16x16x16f16(w1f[c], af.h, ZC, 0, 0, 0);

        // ---- softplus -> f16, packed straight into the two K=32 B-frags ----
        // u[2c],u[2c+1] = packed sp(acc1[c]); h8[0]={c0,c1}, h8[1]={c2,c3}.
        union { half8 h8[2]; uint32 u[8]; } hb;
        #pragma unroll
        for (int c = 0; c < 4; ++c) {
            hb.u[2 * c + 0] = __builtin_bit_cast(uint32,
                __builtin_amdgcn_cvt_pkrtz(sp_log2(acc1[c][0]), sp_log2(acc1[c][1])));
            hb.u[2 * c + 1] = __builtin_bit_cast(uint32,
                __builtin_amdgcn_cvt_pkrtz(sp_log2(acc1[c][2]), sp_log2(acc1[c][3])));
        }

        // ---- layer 2, swapped K=32: acc2[nt] = W2^T * h1^T + b2 ----
        f32x4 acc2[4];
        #pragma unroll
        for (int nt = 0; nt < 4; ++nt)
            acc2[nt] = __builtin_amdgcn_mfma_f32_16x16x32_f16(w2a[0][nt], hb.h8[0], b2c[nt], 0, 0, 0);
        #pragma unroll
        for (int nt = 0; nt < 4; ++nt)
            acc2[nt] = __builtin_amdgcn_mfma_f32_16x16x32_f16(w2a[1][nt], hb.h8[1], acc2[nt], 0, 0, 0);

        // ---- layer 3 as lane-local VALU: s = b3 + sum sp(acc2)*W3*ln2 ----
        // lane holds hids {16nt+4q+r} for batch column lm.
        float s0 = sInit, s1 = 0.0f;
        #pragma unroll
        for (int nt = 0; nt < 4; ++nt) {
            s0 = fmaf(sp_log2(acc2[nt][0]), w3l[nt][0], s0);
            s1 = fmaf(sp_log2(acc2[nt][1]), w3l[nt][1], s1);
            s0 = fmaf(sp_log2(acc2[nt][2]), w3l[nt][2], s0);
            s1 = fmaf(sp_log2(acc2[nt][3]), w3l[nt][3], s1);
        }
        float s = s0 + s1;
        // xor-16 reduce: q0<->q1 and q2<->q3 (within 32-lane halves).
        const uint32 sw = (uint32)__builtin_amdgcn_ds_swizzle(
            (int)__builtin_bit_cast(uint32, s), 0x401F);
        s += __builtin_bit_cast(float, sw);
        // q0 lanes write half 0 (q0+q1 sum); q2 lanes write half 1 (q2+q3).
        if ((lane & 16) == 0)
            obuf[(lane >> 5) * OSTRIDE + (tg * 16 + lm) * 4 + wave] = s;
    }

    // Single barrier, then sum halves + softplus + f32x4 flush: thread i
    // handles row i, writing out[(blockIdx.x*256+i)*16 + blockIdx.y*4 .. +3].
    __syncthreads();
    const int i = threadIdx.x;
    const f32x4 va = *(const f32x4*)(obuf + 4 * i);
    const f32x4 vb = *(const f32x4*)(obuf + OSTRIDE + 4 * i);
    f32x4 v;
    v.x = softplus_full(va.x + vb.x);
    v.y = softplus_full(va.y + vb.y);
    v.z = softplus_full(va.z + vb.z);
    v.w = softplus_full(va.w + vb.w);
    *(f32x4*)(out + (blockIdx.x * 256 + i) * D + blockIdx.y * 4) = v;
}

extern "C" void kernel_launch(void* const* d_in, const int* in_sizes, int n_in,
                              void* d_out, int out_size, void* d_ws, size_t ws_size,
                              hipStream_t stream) {
    const float* t  = (const float*)d_in[0];
    const float* y  = (const float*)d_in[1];
    const float* W1 = (const float*)d_in[2];
    const float* b1 = (const float*)d_in[3];
    const float* W2 = (const float*)d_in[4];
    const float* b2 = (const float*)d_in[5];
    const float* W3 = (const float*)d_in[6];
    const float* b3 = (const float*)d_in[7];
    float* out = (float*)d_out;

    DiagonalVariance_kernel<<<dim3(NBX, NBY), dim3(256), 0, stream>>>(
        t, y, W1, b1, W2, b2, W3, b3, out);
}

// Round 5
// 189.079 us; speedup vs baseline: 1.8209x; 1.8209x over previous
//
#include <hip/hip_runtime.h>
#include <cmath>

// Problem constants
#define B_TOTAL 262144
#define D 16
#define TE 3
#define H 64

#define TPB 16                       // b-tiles (of 16 rows) per wave
#define NBX (B_TOTAL / 16 / TPB)     // 1024 blocks in x
#define NBY 4                        // d-groups of 4 (4 waves/block, one d each)

#define LOG2E 1.44269504088896340736f
#define LN2   0.693147180559945309417f

// A-frag staging stride in dwords. 10 (40B): banks 10*lm mod 32 all distinct
// for lm=0..15 -> conflict-free ds_read_b64; 8B alignment holds.
#define ARS 10

#define OSTRIDE (TPB * 16 * 4)       // one obuf half (floats)

typedef _Float16 half8  __attribute__((ext_vector_type(8)));
typedef _Float16 half4  __attribute__((ext_vector_type(4)));
typedef __fp16   fp16x2 __attribute__((ext_vector_type(2)));   // cvt_pkrtz return type
typedef float    f32x4  __attribute__((ext_vector_type(4)));
typedef unsigned int uint32;

// log2-domain softplus: log2(1 + 2^xs). Scale factors pre-folded into weights:
// W1,b1,b2 carry log2e; W3 carries ln2; ln2*log2e==1 so W2 is raw.
__device__ __forceinline__ float sp_log2(float xs) {
    return __builtin_amdgcn_logf(1.0f + __builtin_amdgcn_exp2f(xs));
}
// exact softplus for the final (unscaled) output
__device__ __forceinline__ float softplus_full(float x) {
    float e = __builtin_amdgcn_exp2f(-fabsf(x) * LOG2E);
    return fmaxf(x, 0.0f) + LN2 * __builtin_amdgcn_logf(1.0f + e);
}

// R14 = R13's K=32 permuted-K layer 2 (verified correct in R13) with the
// launch-bounds reverted to the proven (256,4) point.
// R13 post-mortem: requesting >=5-6 waves/EU forces a small-VGPR class below
// our ~60-reg live set -> ~75 regs spilled to scratch (FETCH 496MB, WRITE
// 320MB, 2.4x slower). (256,4) gives VGPR cap 128, natural usage ~60, no
// spill. DO NOT raise the 2nd launch_bounds arg on this kernel.
// Dataflow (R12): fully register-resident, both layers swapped:
//   L1: acc1[c] = mfma16x16x16(A=W1^T(+bias row), B=x^T)
//       -> D[hid=16c+4q+r][batch=lm]; D-layout == B-frag layout of next MFMA.
//   L2: 8x mfma_16x16x32_f16 with PERMUTED hid->k mapping
//       hid_in(ks,q,j) = 32ks + 16(j>>2) + 4q + (j&3), so the packed
//       softplus(acc1) halves alias directly as the two K=32 B-frags.
//   L3: lane-local VALU dot with W3*ln2 + one ds_swizzle xor-16 reduce.
__global__ __launch_bounds__(256, 4) void DiagonalVariance_kernel(
    const float* __restrict__ t,   // [B, TE]
    const float* __restrict__ y,   // [B, D]
    const float* __restrict__ W1,  // [D, 4, 64]
    const float* __restrict__ b1,  // [D, 64]
    const float* __restrict__ W2,  // [D, 64, 64]
    const float* __restrict__ b2,  // [D, 64]
    const float* __restrict__ W3,  // [D, 64, 1]
    const float* __restrict__ b3,  // [D, 1]
    float* __restrict__ out)       // [B, D]
{
    __shared__ __align__(16) float obuf[2 * OSTRIDE];       // 8 KB: [half][row_local][dd]
    __shared__ __align__(16) uint32 abuf[256 * ARS];        // 10 KB: [row][{u0_d,u1}x4]

    const int wave = threadIdx.x >> 6;
    const int lane = threadIdx.x & 63;
    const int q    = lane >> 4;
    const int lm   = lane & 15;
    const int d    = blockIdx.y * 4 + wave;
    const bool q0  = (q == 0);

    // ---- cooperative input staging: thread i pre-packs row i's x-frag ----
    {
        const int i    = threadIdx.x;
        const int grow = blockIdx.x * 256 + i;
        const f32x4 yv = *(const f32x4*)(y + grow * D + blockIdx.y * 4);
        const float* tpp = t + grow * TE;
        const float tt0 = tpp[0], tt1 = tpp[1], tt2 = tpp[2];
        const uint32 u1 = __builtin_bit_cast(uint32, __builtin_amdgcn_cvt_pkrtz(tt1, tt2));
        uint32* ab = abuf + i * ARS;
        ab[0] = __builtin_bit_cast(uint32, __builtin_amdgcn_cvt_pkrtz(yv.x, tt0)); ab[1] = u1;
        ab[2] = __builtin_bit_cast(uint32, __builtin_amdgcn_cvt_pkrtz(yv.y, tt0)); ab[3] = u1;
        ab[4] = __builtin_bit_cast(uint32, __builtin_amdgcn_cvt_pkrtz(yv.z, tt0)); ab[5] = u1;
        ab[6] = __builtin_bit_cast(uint32, __builtin_amdgcn_cvt_pkrtz(yv.w, tt0)); ab[7] = u1;
    }

    const float* __restrict__ W1d = W1 + d * (4 * H);
    const float* __restrict__ b1d = b1 + d * H;
    const float* __restrict__ W2d = W2 + d * (H * H);
    const float* __restrict__ b2d = b2 + d * H;
    const float* __restrict__ W3d = W3 + d * H;

    // ---------------- one-time per-wave fragment setup ----------------
    // W1 as L1 A-operand: A[row=hid(16nt+lm)][k=4q+i] = W1[k][hid]*log2e,
    // bias b1*log2e at k=4 (q1,i=0); k>=5 rows zero (kill x garbage lanes).
    half4 w1f[4];
    #pragma unroll
    for (int nt = 0; nt < 4; ++nt) {
        #pragma unroll
        for (int i = 0; i < 4; ++i) {
            const int h = 16 * nt + lm;
            float v = 0.0f;
            if (q == 0)           v = W1d[i * H + h] * LOG2E;
            if (q == 1 && i == 0) v = b1d[h] * LOG2E;
            w1f[nt][i] = (_Float16)v;
        }
    }

    // W2 as L2 A-operand for the K=32 swapped MFMA with permuted K:
    // lane(q,lm) element j holds A[row=hid_out=16nt+lm][k'=8q+j] where the
    // permuted slot k' carries input hid_in = 32ks + 16(j>>2) + 4q + (j&3).
    half8 w2a[2][4];
    #pragma unroll
    for (int ks = 0; ks < 2; ++ks)
        #pragma unroll
        for (int nt = 0; nt < 4; ++nt)
            #pragma unroll
            for (int j = 0; j < 8; ++j)
                w2a[ks][nt][j] = (_Float16)
                    W2d[(32 * ks + 16 * (j >> 2) + 4 * q + (j & 3)) * H + 16 * nt + lm];

    // L2 C operand: b2*log2e, row-indexed (output row = hid_out = 16nt+4q+r).
    const f32x4 ZC = {0.f, 0.f, 0.f, 0.f};
    f32x4 b2c[4];
    #pragma unroll
    for (int nt = 0; nt < 4; ++nt) {
        f32x4 bv = *(const f32x4*)(b2d + 16 * nt + 4 * q);
        b2c[nt] = (f32x4){bv.x * LOG2E, bv.y * LOG2E, bv.z * LOG2E, bv.w * LOG2E};
    }

    // W3*ln2, row-indexed the same way (hid = 16nt+4q+r), for the VALU L3.
    f32x4 w3l[4];
    #pragma unroll
    for (int nt = 0; nt < 4; ++nt) {
        f32x4 wv = *(const f32x4*)(W3d + 16 * nt + 4 * q);
        w3l[nt] = (f32x4){wv.x * LN2, wv.y * LN2, wv.z * LN2, wv.w * LN2};
    }

    // b3 enters the reduce exactly once: init on q0 lanes only.
    const float sInit = ((lane & 48) == 0) ? b3[d] : 0.0f;

    // staged x-frag base for this wave: + tg*16*ARS per tile (imm offset)
    const uint32* const ard = abuf + lm * ARS + 2 * wave;

    __syncthreads();   // staging visible to all waves

    // ---- cross-tile x-frag prefetch ----
    uint32 a0n = ard[0];
    uint32 a1n = ard[1];

    #pragma unroll 1
    for (int tg = 0; tg < TPB; ++tg) {
        const uint32 a0 = a0n;
        const uint32 a1 = a1n;
        {   // issue next tile's read now; latency hides under this tile
            const int tn = (tg + 1 < TPB) ? (tg + 1) : tg;
            a0n = ard[tn * 16 * ARS + 0];
            a1n = ard[tn * 16 * ARS + 1];
        }
        union { half4 h; uint32 u[2]; } af;
        af.u[0] = q0 ? a0 : 0x00003C00u;   // q1: {1.0h,0} bias row k=4
        af.u[1] = q0 ? a1 : 0u;            // q2/q3 garbage killed by zero A rows

        // ---- layer 1, swapped: acc1[c] = D[hid=16c+4q+r][batch=lm] ----
        f32x4 acc1[4];
        #pragma unroll
        for (int c = 0; c < 4; ++c)
            acc1[c] = __builtin_amdgcn_mfma_f32_16x16x16f16(w1f[c], af.h, ZC, 0, 0, 0);

        // ---- softplus -> f16, packed straight into the two K=32 B-frags ----
        // u[2c],u[2c+1] = packed sp(acc1[c]); h8[0]={c0,c1}, h8[1]={c2,c3}.
        union { half8 h8[2]; uint32 u[8]; } hb;
        #pragma unroll
        for (int c = 0; c < 4; ++c) {
            hb.u[2 * c + 0] = __builtin_bit_cast(uint32,
                __builtin_amdgcn_cvt_pkrtz(sp_log2(acc1[c][0]), sp_log2(acc1[c][1])));
            hb.u[2 * c + 1] = __builtin_bit_cast(uint32,
                __builtin_amdgcn_cvt_pkrtz(sp_log2(acc1[c][2]), sp_log2(acc1[c][3])));
        }

        // ---- layer 2, swapped K=32: acc2[nt] = W2^T * h1^T + b2 ----
        f32x4 acc2[4];
        #pragma unroll
        for (int nt = 0; nt < 4; ++nt)
            acc2[nt] = __builtin_amdgcn_mfma_f32_16x16x32_f16(w2a[0][nt], hb.h8[0], b2c[nt], 0, 0, 0);
        #pragma unroll
        for (int nt = 0; nt < 4; ++nt)
            acc2[nt] = __builtin_amdgcn_mfma_f32_16x16x32_f16(w2a[1][nt], hb.h8[1], acc2[nt], 0, 0, 0);

        // ---- layer 3 as lane-local VALU: s = b3 + sum sp(acc2)*W3*ln2 ----
        // lane holds hids {16nt+4q+r} for batch column lm.
        float s0 = sInit, s1 = 0.0f;
        #pragma unroll
        for (int nt = 0; nt < 4; ++nt) {
            s0 = fmaf(sp_log2(acc2[nt][0]), w3l[nt][0], s0);
            s1 = fmaf(sp_log2(acc2[nt][1]), w3l[nt][1], s1);
            s0 = fmaf(sp_log2(acc2[nt][2]), w3l[nt][2], s0);
            s1 = fmaf(sp_log2(acc2[nt][3]), w3l[nt][3], s1);
        }
        float s = s0 + s1;
        // xor-16 reduce: q0<->q1 and q2<->q3 (within 32-lane halves).
        const uint32 sw = (uint32)__builtin_amdgcn_ds_swizzle(
            (int)__builtin_bit_cast(uint32, s), 0x401F);
        s += __builtin_bit_cast(float, sw);
        // q0 lanes write half 0 (q0+q1 sum); q2 lanes write half 1 (q2+q3).
        if ((lane & 16) == 0)
            obuf[(lane >> 5) * OSTRIDE + (tg * 16 + lm) * 4 + wave] = s;
    }

    // Single barrier, then sum halves + softplus + f32x4 flush: thread i
    // handles row i, writing out[(blockIdx.x*256+i)*16 + blockIdx.y*4 .. +3].
    __syncthreads();
    const int i = threadIdx.x;
    const f32x4 va = *(const f32x4*)(obuf + 4 * i);
    const f32x4 vb = *(const f32x4*)(obuf + OSTRIDE + 4 * i);
    f32x4 v;
    v.x = softplus_full(va.x + vb.x);
    v.y = softplus_full(va.y + vb.y);
    v.z = softplus_full(va.z + vb.z);
    v.w = softplus_full(va.w + vb.w);
    *(f32x4*)(out + (blockIdx.x * 256 + i) * D + blockIdx.y * 4) = v;
}

extern "C" void kernel_launch(void* const* d_in, const int* in_sizes, int n_in,
                              void* d_out, int out_size, void* d_ws, size_t ws_size,
                              hipStream_t stream) {
    const float* t  = (const float*)d_in[0];
    const float* y  = (const float*)d_in[1];
    const float* W1 = (const float*)d_in[2];
    const float* b1 = (const float*)d_in[3];
    const float* W2 = (const float*)d_in[4];
    const float* b2 = (const float*)d_in[5];
    const float* W3 = (const float*)d_in[6];
    const float* b3 = (const float*)d_in[7];
    float* out = (float*)d_out;

    DiagonalVariance_kernel<<<dim3(NBX, NBY), dim3(256), 0, stream>>>(
        t, y, W1, b1, W2, b2, W3, b3, out);
}

// Round 6
// 188.302 us; speedup vs baseline: 1.8285x; 1.0041x over previous
//
#include <hip/hip_runtime.h>
#include <cmath>

// Problem constants
#define B_TOTAL 262144
#define D 16
#define TE 3
#define H 64

#define TPB 16                       // b-tiles (of 16 rows) per wave
#define NBX (B_TOTAL / 16 / TPB)     // 1024 blocks in x
#define NBY 4                        // d-groups of 4 (4 waves/block, one d each)

#define LOG2E 1.44269504088896340736f
#define LN2   0.693147180559945309417f

// A-frag staging stride in dwords. 10 (40B): banks 10*lm mod 32 all distinct
// for lm=0..15 -> conflict-free ds_read_b64; 8B alignment holds.
#define ARS 10

#define OSTRIDE (TPB * 16 * 4)       // one obuf half (floats)

typedef _Float16 half8  __attribute__((ext_vector_type(8)));
typedef _Float16 half4  __attribute__((ext_vector_type(4)));
typedef __fp16   fp16x2 __attribute__((ext_vector_type(2)));   // cvt_pkrtz return type
typedef float    f32x4  __attribute__((ext_vector_type(4)));
typedef unsigned int uint32;
typedef unsigned int uint32x2 __attribute__((ext_vector_type(2)));

// log2-domain softplus: log2(1 + 2^xs). Scale factors pre-folded into weights:
// W1,b1,b2 carry log2e; W3 carries ln2; ln2*log2e==1 so W2 is raw.
__device__ __forceinline__ float sp_log2(float xs) {
    return __builtin_amdgcn_logf(1.0f + __builtin_amdgcn_exp2f(xs));
}
// exact softplus for the final (unscaled) output
__device__ __forceinline__ float softplus_full(float x) {
    float e = __builtin_amdgcn_exp2f(-fabsf(x) * LOG2E);
    return fmaxf(x, 0.0f) + LN2 * __builtin_amdgcn_logf(1.0f + e);
}

// R15 = R14 with the tile-end reduce moved off the DS pipe.
// R14 audit: idle ~19% is occupancy-invariant (R10/R12/R14) -> correlated
// per-tile stall. Culprit: ds_swizzle xor-16 reduce. DS ops complete in-order
// per wave, so waiting on the swizzle also waits on the just-issued next-tile
// prefetch ds_reads: ~100cy blocking round-trip per tile + defeated prefetch.
// Fix: xor-32 restructure via v_permlane32_swap_b32 (VALU, no lgkm):
//   s[lane] += s[lane^32]  ->  lanes 0-15 = q0+q2, lanes 16-31 = q1+q3;
//   lanes 0-31 write the two obuf halves; flush sums halves (total over q).
// Register law (R13 disaster): VGPR cap ~= 256 / launch_bounds_waves_per_EU
// (4->64, 5->48, 6->40). We use exactly 64: KEEP (256,4), no extra live state.
__global__ __launch_bounds__(256, 4) void DiagonalVariance_kernel(
    const float* __restrict__ t,   // [B, TE]
    const float* __restrict__ y,   // [B, D]
    const float* __restrict__ W1,  // [D, 4, 64]
    const float* __restrict__ b1,  // [D, 64]
    const float* __restrict__ W2,  // [D, 64, 64]
    const float* __restrict__ b2,  // [D, 64]
    const float* __restrict__ W3,  // [D, 64, 1]
    const float* __restrict__ b3,  // [D, 1]
    float* __restrict__ out)       // [B, D]
{
    __shared__ __align__(16) float obuf[2 * OSTRIDE];       // 8 KB: [half][row_local][dd]
    __shared__ __align__(16) uint32 abuf[256 * ARS];        // 10 KB: [row][{u0_d,u1}x4]

    const int wave = threadIdx.x >> 6;
    const int lane = threadIdx.x & 63;
    const int q    = lane >> 4;
    const int lm   = lane & 15;
    const int d    = blockIdx.y * 4 + wave;
    const bool q0  = (q == 0);
    const bool lo32 = (lane < 32);

    // ---- cooperative input staging: thread i pre-packs row i's x-frag ----
    {
        const int i    = threadIdx.x;
        const int grow = blockIdx.x * 256 + i;
        const f32x4 yv = *(const f32x4*)(y + grow * D + blockIdx.y * 4);
        const float* tpp = t + grow * TE;
        const float tt0 = tpp[0], tt1 = tpp[1], tt2 = tpp[2];
        const uint32 u1 = __builtin_bit_cast(uint32, __builtin_amdgcn_cvt_pkrtz(tt1, tt2));
        uint32* ab = abuf + i * ARS;
        ab[0] = __builtin_bit_cast(uint32, __builtin_amdgcn_cvt_pkrtz(yv.x, tt0)); ab[1] = u1;
        ab[2] = __builtin_bit_cast(uint32, __builtin_amdgcn_cvt_pkrtz(yv.y, tt0)); ab[3] = u1;
        ab[4] = __builtin_bit_cast(uint32, __builtin_amdgcn_cvt_pkrtz(yv.z, tt0)); ab[5] = u1;
        ab[6] = __builtin_bit_cast(uint32, __builtin_amdgcn_cvt_pkrtz(yv.w, tt0)); ab[7] = u1;
    }

    const float* __restrict__ W1d = W1 + d * (4 * H);
    const float* __restrict__ b1d = b1 + d * H;
    const float* __restrict__ W2d = W2 + d * (H * H);
    const float* __restrict__ b2d = b2 + d * H;
    const float* __restrict__ W3d = W3 + d * H;

    // ---------------- one-time per-wave fragment setup ----------------
    // W1 as L1 A-operand: A[row=hid(16nt+lm)][k=4q+i] = W1[k][hid]*log2e,
    // bias b1*log2e at k=4 (q1,i=0); k>=5 rows zero (kill x garbage lanes).
    half4 w1f[4];
    #pragma unroll
    for (int nt = 0; nt < 4; ++nt) {
        #pragma unroll
        for (int i = 0; i < 4; ++i) {
            const int h = 16 * nt + lm;
            float v = 0.0f;
            if (q == 0)           v = W1d[i * H + h] * LOG2E;
            if (q == 1 && i == 0) v = b1d[h] * LOG2E;
            w1f[nt][i] = (_Float16)v;
        }
    }

    // W2 as L2 A-operand for the K=32 swapped MFMA with permuted K:
    // lane(q,lm) element j holds A[row=hid_out=16nt+lm][k'=8q+j] where the
    // permuted slot k' carries input hid_in = 32ks + 16(j>>2) + 4q + (j&3).
    half8 w2a[2][4];
    #pragma unroll
    for (int ks = 0; ks < 2; ++ks)
        #pragma unroll
        for (int nt = 0; nt < 4; ++nt)
            #pragma unroll
            for (int j = 0; j < 8; ++j)
                w2a[ks][nt][j] = (_Float16)
                    W2d[(32 * ks + 16 * (j >> 2) + 4 * q + (j & 3)) * H + 16 * nt + lm];

    // L2 C operand: b2*log2e, row-indexed (output row = hid_out = 16nt+4q+r).
    const f32x4 ZC = {0.f, 0.f, 0.f, 0.f};
    f32x4 b2c[4];
    #pragma unroll
    for (int nt = 0; nt < 4; ++nt) {
        f32x4 bv = *(const f32x4*)(b2d + 16 * nt + 4 * q);
        b2c[nt] = (f32x4){bv.x * LOG2E, bv.y * LOG2E, bv.z * LOG2E, bv.w * LOG2E};
    }

    // W3*ln2, row-indexed the same way (hid = 16nt+4q+r), for the VALU L3.
    f32x4 w3l[4];
    #pragma unroll
    for (int nt = 0; nt < 4; ++nt) {
        f32x4 wv = *(const f32x4*)(W3d + 16 * nt + 4 * q);
        w3l[nt] = (f32x4){wv.x * LN2, wv.y * LN2, wv.z * LN2, wv.w * LN2};
    }

    // b3 enters the reduce exactly once: init on q0 lanes only.
    const float sInit = ((lane & 48) == 0) ? b3[d] : 0.0f;

    // staged x-frag base for this wave: + tg*16*ARS per tile (imm offset)
    const uint32* const ard = abuf + lm * ARS + 2 * wave;

    __syncthreads();   // staging visible to all waves

    // ---- cross-tile x-frag prefetch ----
    uint32 a0n = ard[0];
    uint32 a1n = ard[1];

    #pragma unroll 1
    for (int tg = 0; tg < TPB; ++tg) {
        const uint32 a0 = a0n;
        const uint32 a1 = a1n;
        {   // issue next tile's read now; latency hides under this tile
            const int tn = (tg + 1 < TPB) ? (tg + 1) : tg;
            a0n = ard[tn * 16 * ARS + 0];
            a1n = ard[tn * 16 * ARS + 1];
        }
        union { half4 h; uint32 u[2]; } af;
        af.u[0] = q0 ? a0 : 0x00003C00u;   // q1: {1.0h,0} bias row k=4
        af.u[1] = q0 ? a1 : 0u;            // q2/q3 garbage killed by zero A rows

        // ---- layer 1, swapped: acc1[c] = D[hid=16c+4q+r][batch=lm] ----
        f32x4 acc1[4];
        #pragma unroll
        for (int c = 0; c < 4; ++c)
            acc1[c] = __builtin_amdgcn_mfma_f32_16x16x16f16(w1f[c], af.h, ZC, 0, 0, 0);

        // ---- softplus -> f16, packed straight into the two K=32 B-frags ----
        // u[2c],u[2c+1] = packed sp(acc1[c]); h8[0]={c0,c1}, h8[1]={c2,c3}.
        union { half8 h8[2]; uint32 u[8]; } hb;
        #pragma unroll
        for (int c = 0; c < 4; ++c) {
            hb.u[2 * c + 0] = __builtin_bit_cast(uint32,
                __builtin_amdgcn_cvt_pkrtz(sp_log2(acc1[c][0]), sp_log2(acc1[c][1])));
            hb.u[2 * c + 1] = __builtin_bit_cast(uint32,
                __builtin_amdgcn_cvt_pkrtz(sp_log2(acc1[c][2]), sp_log2(acc1[c][3])));
        }

        // ---- layer 2, swapped K=32: acc2[nt] = W2^T * h1^T + b2 ----
        f32x4 acc2[4];
        #pragma unroll
        for (int nt = 0; nt < 4; ++nt)
            acc2[nt] = __builtin_amdgcn_mfma_f32_16x16x32_f16(w2a[0][nt], hb.h8[0], b2c[nt], 0, 0, 0);
        #pragma unroll
        for (int nt = 0; nt < 4; ++nt)
            acc2[nt] = __builtin_amdgcn_mfma_f32_16x16x32_f16(w2a[1][nt], hb.h8[1], acc2[nt], 0, 0, 0);

        // ---- layer 3 as lane-local VALU: s = b3 + sum sp(acc2)*W3*ln2 ----
        // lane holds hids {16nt+4q+r} for batch column lm.
        float s0 = sInit, s1 = 0.0f;
        #pragma unroll
        for (int nt = 0; nt < 4; ++nt) {
            s0 = fmaf(sp_log2(acc2[nt][0]), w3l[nt][0], s0);
            s1 = fmaf(sp_log2(acc2[nt][1]), w3l[nt][1], s1);
            s0 = fmaf(sp_log2(acc2[nt][2]), w3l[nt][2], s0);
            s1 = fmaf(sp_log2(acc2[nt][3]), w3l[nt][3], s1);
        }
        float s = s0 + s1;

        // xor-32 reduce on the VALU pipe: v_permlane32_swap_b32 exchanges
        // vdst upper 32 lanes with vsrc lower 32 lanes. With both args = s:
        //   pr.x[lane>=32] = s[lane-32];  pr.y[lane<32] = s[lane+32]
        // so partner(lane^32) = lo32 ? pr.y : pr.x. No lgkm wait.
        const uint32x2 pr = __builtin_amdgcn_permlane32_swap(
            __builtin_bit_cast(uint32, s), __builtin_bit_cast(uint32, s),
            false, false);
        s += __builtin_bit_cast(float, lo32 ? pr.y : pr.x);

        // lanes 0-15 hold q0+q2 -> half 0; lanes 16-31 hold q1+q3 -> half 1.
        if (lo32)
            obuf[((lane >> 4) & 1) * OSTRIDE + (tg * 16 + lm) * 4 + wave] = s;
    }

    // Single barrier, then sum halves + softplus + f32x4 flush: thread i
    // handles row i, writing out[(blockIdx.x*256+i)*16 + blockIdx.y*4 .. +3].
    __syncthreads();
    const int i = threadIdx.x;
    const f32x4 va = *(const f32x4*)(obuf + 4 * i);
    const f32x4 vb = *(const f32x4*)(obuf + OSTRIDE + 4 * i);
    f32x4 v;
    v.x = softplus_full(va.x + vb.x);
    v.y = softplus_full(va.y + vb.y);
    v.z = softplus_full(va.z + vb.z);
    v.w = softplus_full(va.w + vb.w);
    *(f32x4*)(out + (blockIdx.x * 256 + i) * D + blockIdx.y * 4) = v;
}

extern "C" void kernel_launch(void* const* d_in, const int* in_sizes, int n_in,
                              void* d_out, int out_size, void* d_ws, size_t ws_size,
                              hipStream_t stream) {
    const float* t  = (const float*)d_in[0];
    const float* y  = (const float*)d_in[1];
    const float* W1 = (const float*)d_in[2];
    const float* b1 = (const float*)d_in[3];
    const float* W2 = (const float*)d_in[4];
    const float* b2 = (const float*)d_in[5];
    const float* W3 = (const float*)d_in[6];
    const float* b3 = (const float*)d_in[7];
    float* out = (float*)d_out;

    DiagonalVariance_kernel<<<dim3(NBX, NBY), dim3(256), 0, stream>>>(
        t, y, W1, b1, W2, b2, W3, b3, out);
}

// Round 7
// 184.553 us; speedup vs baseline: 1.8656x; 1.0203x over previous
//
#include <hip/hip_runtime.h>
#include <cmath>

// Problem constants
#define B_TOTAL 262144
#define D 16
#define TE 3
#define H 64

#define TPB 16                       // b-tiles (of 16 rows) per wave
#define NBX (B_TOTAL / 16 / TPB)     // 1024 blocks in x
#define NBY 4                        // d-groups of 4 (4 waves/block, one d each)

#define LOG2E 1.44269504088896340736f
#define LN2   0.693147180559945309417f

// A-frag staging stride in dwords. 10 (40B): banks 10*lm mod 32 all distinct
// for lm=0..15 -> conflict-free ds_read_b64; 8B alignment holds.
#define ARS 10

#define OSTRIDE (TPB * 16 * 4)       // one obuf half (floats)

typedef _Float16 half8  __attribute__((ext_vector_type(8)));
typedef _Float16 half4  __attribute__((ext_vector_type(4)));
typedef __fp16   fp16x2 __attribute__((ext_vector_type(2)));   // cvt_pkrtz return type
typedef float    f32x4  __attribute__((ext_vector_type(4)));
typedef float    f32x2  __attribute__((ext_vector_type(2)));
typedef unsigned int uint32;
typedef unsigned int uint32x2 __attribute__((ext_vector_type(2)));

// log2-domain softplus, pairwise: log2(1 + 2^x) for two values; the +1 adds
// pack into one v_pk_add_f32.
__device__ __forceinline__ f32x2 sp2(float a, float b) {
    f32x2 e = { __builtin_amdgcn_exp2f(a), __builtin_amdgcn_exp2f(b) };
    e += (f32x2){1.0f, 1.0f};
    return (f32x2){ __builtin_amdgcn_logf(e.x), __builtin_amdgcn_logf(e.y) };
}
// exact softplus for the final (unscaled) output
__device__ __forceinline__ float softplus_full(float x) {
    float e = __builtin_amdgcn_exp2f(-fabsf(x) * LOG2E);
    return fmaxf(x, 0.0f) + LN2 * __builtin_amdgcn_logf(1.0f + e);
}

// R16 = R15 with three changes from the R15 post-mortem:
//  1. obuf writer fix: after the xor-32 permlane reduce, q0 lanes hold q0+q2
//     and q3 lanes hold q3+q1. Writing from q0 AND q3 (instead of lanes 0-31)
//     splits the writers across the wave's two 32-lane LDS passes -> back to
//     the 2-way-free bank profile (R15's lanes-0-31 writers were 4-way:
//     OSTRIDE=4096B aliases to bank 0).
//  2. __launch_bounds__(256,3) + #pragma unroll 2: idle ~20% is cross-tile
//     serialization (unroll 1 closes each tile's DAG; tile t+1's L1 MFMAs
//     can't issue under tile t's L3 trans chain). Cap 85 regs gives the
//     scheduler room for the 2-tile window; occupancy only 40%->37.5% since
//     4 waves/EU was never achieved. Register law: cap = 256/bound (R13).
//  3. f32x2 packing of the softplus +1 adds and the L3 dot (pk_add/pk_fma).
// Dataflow unchanged (R12/R14): register-resident, both layers swapped, K=32
// permuted-K L2, lane-local VALU L3, permlane32 xor-32 reduce.
__global__ __launch_bounds__(256, 3) void DiagonalVariance_kernel(
    const float* __restrict__ t,   // [B, TE]
    const float* __restrict__ y,   // [B, D]
    const float* __restrict__ W1,  // [D, 4, 64]
    const float* __restrict__ b1,  // [D, 64]
    const float* __restrict__ W2,  // [D, 64, 64]
    const float* __restrict__ b2,  // [D, 64]
    const float* __restrict__ W3,  // [D, 64, 1]
    const float* __restrict__ b3,  // [D, 1]
    float* __restrict__ out)       // [B, D]
{
    __shared__ __align__(16) float obuf[2 * OSTRIDE];       // 8 KB: [half][row_local][dd]
    __shared__ __align__(16) uint32 abuf[256 * ARS];        // 10 KB: [row][{u0_d,u1}x4]

    const int wave = threadIdx.x >> 6;
    const int lane = threadIdx.x & 63;
    const int q    = lane >> 4;
    const int lm   = lane & 15;
    const int d    = blockIdx.y * 4 + wave;
    const bool q0  = (q == 0);
    const bool lo32 = (lane < 32);

    // ---- cooperative input staging: thread i pre-packs row i's x-frag ----
    {
        const int i    = threadIdx.x;
        const int grow = blockIdx.x * 256 + i;
        const f32x4 yv = *(const f32x4*)(y + grow * D + blockIdx.y * 4);
        const float* tpp = t + grow * TE;
        const float tt0 = tpp[0], tt1 = tpp[1], tt2 = tpp[2];
        const uint32 u1 = __builtin_bit_cast(uint32, __builtin_amdgcn_cvt_pkrtz(tt1, tt2));
        uint32* ab = abuf + i * ARS;
        ab[0] = __builtin_bit_cast(uint32, __builtin_amdgcn_cvt_pkrtz(yv.x, tt0)); ab[1] = u1;
        ab[2] = __builtin_bit_cast(uint32, __builtin_amdgcn_cvt_pkrtz(yv.y, tt0)); ab[3] = u1;
        ab[4] = __builtin_bit_cast(uint32, __builtin_amdgcn_cvt_pkrtz(yv.z, tt0)); ab[5] = u1;
        ab[6] = __builtin_bit_cast(uint32, __builtin_amdgcn_cvt_pkrtz(yv.w, tt0)); ab[7] = u1;
    }

    const float* __restrict__ W1d = W1 + d * (4 * H);
    const float* __restrict__ b1d = b1 + d * H;
    const float* __restrict__ W2d = W2 + d * (H * H);
    const float* __restrict__ b2d = b2 + d * H;
    const float* __restrict__ W3d = W3 + d * H;

    // ---------------- one-time per-wave fragment setup ----------------
    // W1 as L1 A-operand: A[row=hid(16nt+lm)][k=4q+i] = W1[k][hid]*log2e,
    // bias b1*log2e at k=4 (q1,i=0); k>=5 rows zero (kill x garbage lanes).
    half4 w1f[4];
    #pragma unroll
    for (int nt = 0; nt < 4; ++nt) {
        #pragma unroll
        for (int i = 0; i < 4; ++i) {
            const int h = 16 * nt + lm;
            float v = 0.0f;
            if (q == 0)           v = W1d[i * H + h] * LOG2E;
            if (q == 1 && i == 0) v = b1d[h] * LOG2E;
            w1f[nt][i] = (_Float16)v;
        }
    }

    // W2 as L2 A-operand for the K=32 swapped MFMA with permuted K:
    // lane(q,lm) element j holds A[row=hid_out=16nt+lm][k'=8q+j] where the
    // permuted slot k' carries input hid_in = 32ks + 16(j>>2) + 4q + (j&3).
    half8 w2a[2][4];
    #pragma unroll
    for (int ks = 0; ks < 2; ++ks)
        #pragma unroll
        for (int nt = 0; nt < 4; ++nt)
            #pragma unroll
            for (int j = 0; j < 8; ++j)
                w2a[ks][nt][j] = (_Float16)
                    W2d[(32 * ks + 16 * (j >> 2) + 4 * q + (j & 3)) * H + 16 * nt + lm];

    // L2 C operand: b2*log2e, row-indexed (output row = hid_out = 16nt+4q+r).
    const f32x4 ZC = {0.f, 0.f, 0.f, 0.f};
    f32x4 b2c[4];
    #pragma unroll
    for (int nt = 0; nt < 4; ++nt) {
        f32x4 bv = *(const f32x4*)(b2d + 16 * nt + 4 * q);
        b2c[nt] = (f32x4){bv.x * LOG2E, bv.y * LOG2E, bv.z * LOG2E, bv.w * LOG2E};
    }

    // W3*ln2, row-indexed the same way (hid = 16nt+4q+r), for the VALU L3.
    f32x4 w3l[4];
    #pragma unroll
    for (int nt = 0; nt < 4; ++nt) {
        f32x4 wv = *(const f32x4*)(W3d + 16 * nt + 4 * q);
        w3l[nt] = (f32x4){wv.x * LN2, wv.y * LN2, wv.z * LN2, wv.w * LN2};
    }

    // b3 enters the reduce exactly once: init on q0 lanes only.
    const float sInit = ((lane & 48) == 0) ? b3[d] : 0.0f;

    // staged x-frag base for this wave: + tg*16*ARS per tile (imm offset)
    const uint32* const ard = abuf + lm * ARS + 2 * wave;

    __syncthreads();   // staging visible to all waves

    // ---- cross-tile x-frag prefetch ----
    uint32 a0n = ard[0];
    uint32 a1n = ard[1];

    #pragma unroll 2
    for (int tg = 0; tg < TPB; ++tg) {
        const uint32 a0 = a0n;
        const uint32 a1 = a1n;
        {   // issue next tile's read now; latency hides under this tile
            const int tn = (tg + 1 < TPB) ? (tg + 1) : tg;
            a0n = ard[tn * 16 * ARS + 0];
            a1n = ard[tn * 16 * ARS + 1];
        }
        union { half4 h; uint32 u[2]; } af;
        af.u[0] = q0 ? a0 : 0x00003C00u;   // q1: {1.0h,0} bias row k=4
        af.u[1] = q0 ? a1 : 0u;            // q2/q3 garbage killed by zero A rows

        // ---- layer 1, swapped: acc1[c] = D[hid=16c+4q+r][batch=lm] ----
        f32x4 acc1[4];
        #pragma unroll
        for (int c = 0; c < 4; ++c)
            acc1[c] = __builtin_amdgcn_mfma_f32_16x16x16f16(w1f[c], af.h, ZC, 0, 0, 0);

        // ---- softplus -> f16, packed straight into the two K=32 B-frags ----
        // u[2c],u[2c+1] = packed sp(acc1[c]); h8[0]={c0,c1}, h8[1]={c2,c3}.
        union { half8 h8[2]; uint32 u[8]; } hb;
        #pragma unroll
        for (int c = 0; c < 4; ++c) {
            const f32x2 p01 = sp2(acc1[c][0], acc1[c][1]);
            const f32x2 p23 = sp2(acc1[c][2], acc1[c][3]);
            hb.u[2 * c + 0] = __builtin_bit_cast(uint32,
                __builtin_amdgcn_cvt_pkrtz(p01.x, p01.y));
            hb.u[2 * c + 1] = __builtin_bit_cast(uint32,
                __builtin_amdgcn_cvt_pkrtz(p23.x, p23.y));
        }

        // ---- layer 2, swapped K=32: acc2[nt] = W2^T * h1^T + b2 ----
        f32x4 acc2[4];
        #pragma unroll
        for (int nt = 0; nt < 4; ++nt)
            acc2[nt] = __builtin_amdgcn_mfma_f32_16x16x32_f16(w2a[0][nt], hb.h8[0], b2c[nt], 0, 0, 0);
        #pragma unroll
        for (int nt = 0; nt < 4; ++nt)
            acc2[nt] = __builtin_amdgcn_mfma_f32_16x16x32_f16(w2a[1][nt], hb.h8[1], acc2[nt], 0, 0, 0);

        // ---- layer 3 as lane-local VALU: s = b3 + sum sp(acc2)*W3*ln2 ----
        // lane holds hids {16nt+4q+r} for batch column lm; f32x2 pk_fma dot.
        f32x2 s01 = {sInit, 0.0f};
        #pragma unroll
        for (int nt = 0; nt < 4; ++nt) {
            const f32x2 pA = sp2(acc2[nt][0], acc2[nt][1]);
            const f32x2 wA = {w3l[nt][0], w3l[nt][1]};
            s01 = __builtin_elementwise_fma(pA, wA, s01);
            const f32x2 pB = sp2(acc2[nt][2], acc2[nt][3]);
            const f32x2 wB = {w3l[nt][2], w3l[nt][3]};
            s01 = __builtin_elementwise_fma(pB, wB, s01);
        }
        float s = s01.x + s01.y;

        // xor-32 reduce on the VALU pipe: v_permlane32_swap_b32 exchanges
        // vdst upper 32 lanes with vsrc lower 32 lanes. With both args = s:
        //   pr.x[lane>=32] = s[lane-32];  pr.y[lane<32] = s[lane+32]
        // so partner(lane^32) = lo32 ? pr.y : pr.x. No lgkm wait.
        const uint32x2 pr = __builtin_amdgcn_permlane32_swap(
            __builtin_bit_cast(uint32, s), __builtin_bit_cast(uint32, s),
            false, false);
        s += __builtin_bit_cast(float, lo32 ? pr.y : pr.x);

        // Writers split across the wave's two 32-lane LDS passes (2-way-free):
        // q0 lanes hold q0+q2 -> half 0; q3 lanes hold q3+q1 -> half 1.
        if (q == 0 || q == 3)
            obuf[(q >> 1) * OSTRIDE + (tg * 16 + lm) * 4 + wave] = s;
    }

    // Single barrier, then sum halves + softplus + f32x4 flush: thread i
    // handles row i, writing out[(blockIdx.x*256+i)*16 + blockIdx.y*4 .. +3].
    __syncthreads();
    const int i = threadIdx.x;
    const f32x4 va = *(const f32x4*)(obuf + 4 * i);
    const f32x4 vb = *(const f32x4*)(obuf + OSTRIDE + 4 * i);
    f32x4 v;
    v.x = softplus_full(va.x + vb.x);
    v.y = softplus_full(va.y + vb.y);
    v.z = softplus_full(va.z + vb.z);
    v.w = softplus_full(va.w + vb.w);
    *(f32x4*)(out + (blockIdx.x * 256 + i) * D + blockIdx.y * 4) = v;
}

extern "C" void kernel_launch(void* const* d_in, const int* in_sizes, int n_in,
                              void* d_out, int out_size, void* d_ws, size_t ws_size,
                              hipStream_t stream) {
    const float* t  = (const float*)d_in[0];
    const float* y  = (const float*)d_in[1];
    const float* W1 = (const float*)d_in[2];
    const float* b1 = (const float*)d_in[3];
    const float* W2 = (const float*)d_in[4];
    const float* b2 = (const float*)d_in[5];
    const float* W3 = (const float*)d_in[6];
    const float* b3 = (const float*)d_in[7];
    float* out = (float*)d_out;

    DiagonalVariance_kernel<<<dim3(NBX, NBY), dim3(256), 0, stream>>>(
        t, y, W1, b1, W2, b2, W3, b3, out);
}